// Round 6
// baseline (568.414 us; speedup 1.0000x reference)
//
#include <hip/hip_runtime.h>

#define DIM   256
#define BATCH 16
#define NPX   (DIM*DIM)

// padded ws layout: rows gy+12 in [0,280), col stride 284 (16B-aligned rows)
// fields use col offset +12 (tile col base bx*64 -> aligned float4)
// coeffs use col offset +13 (epilogue col base bx*64-9+4cg -> aligned float4)
#define PR   280
#define PC   284
#define PBS  (PR*PC)                 // 79520 floats per batch
#define NPAD ((size_t)BATCH*PBS)     // 1,272,320 floats per array

// LDS tile: 88x88 region used, 90 rows (2 pad-read rows), stride 92 (16B-aligned)
#define LR 90
#define LC 92

// Collapse the 14 used fd_kernels into one effective 7x7 kernel.
// eff[t] = sum_{c=1..14} fdk[c,0,t] * cw[c-1]   (kernel 0 unused: u1fd[:,1:])
__global__ void prep_eff(const float* __restrict__ fdk,
                         const float* __restrict__ cw,
                         float* __restrict__ eff) {
    int t = threadIdx.x;
    if (t < 49) {
        float s = 0.f;
        #pragma unroll
        for (int c = 1; c < 15; ++c)
            s += fdk[c * 49 + t] * cw[c - 1];
        eff[t] = s;
    }
}

// Streaming prologue: build padded A1/A0 (= u1,u0 with zero border), zero B1/B0,
// and precompute D1 = 1/(4e+sg), G = (4e-sg)*D1 into padded CD/CG.
// 1 float4 cell per thread, huge TLP -> takes the cold-HBM hit at near-BW.
__global__ __launch_bounds__(256) void prologue(
    const float* __restrict__ u1, const float* __restrict__ u0,
    const float* __restrict__ epsr, const float* __restrict__ sigma,
    float* __restrict__ A1, float* __restrict__ A0,
    float* __restrict__ B1, float* __restrict__ B0,
    float* __restrict__ CD, float* __restrict__ CG)
{
    const int i4 = blockIdx.x * 256 + threadIdx.x;
    const int percb = PR * (PC / 4);            // 19,880 float4 per batch
    if (i4 >= BATCH * percb) return;
    const int b   = i4 / percb;
    const int rem = i4 - b * percb;
    const int row = rem / (PC / 4);
    const int col = (rem - row * (PC / 4)) * 4;
    const size_t cell = (size_t)b * PBS + (size_t)row * PC + col;
    const size_t gb   = (size_t)b * NPX;
    const int gy = row - 12;

    float f1[4], f0[4], cd[4], cg2[4];
    #pragma unroll
    for (int j = 0; j < 4; ++j) {
        const int gxf = col + j - 12;           // field col
        const int gxc = col + j - 13;           // coeff col
        float v1 = 0.f, v0 = 0.f, d = 0.f, g = 0.f;
        if (gy >= 0 && gy < DIM && gxf >= 0 && gxf < DIM) {
            v1 = u1[gb + gy * DIM + gxf];
            v0 = u0[gb + gy * DIM + gxf];
        }
        if (gy >= 0 && gy < DIM && gxc >= 0 && gxc < DIM) {
            const float e = epsr[gb + gy * DIM + gxc];
            const float s = sigma[gb + gy * DIM + gxc];
            d = 1.f / (4.f * e + s);            // exact div once, reused 32x
            g = (4.f * e - s) * d;
        }
        f1[j] = v1; f0[j] = v0; cd[j] = d; cg2[j] = g;
    }
    *(float4*)&A1[cell] = make_float4(f1[0], f1[1], f1[2], f1[3]);
    *(float4*)&A0[cell] = make_float4(f0[0], f0[1], f0[2], f0[3]);
    *(float4*)&CD[cell] = make_float4(cd[0], cd[1], cd[2], cd[3]);
    *(float4*)&CG[cell] = make_float4(cg2[0], cg2[1], cg2[2], cg2[3]);
    const float4 z = make_float4(0.f, 0.f, 0.f, 0.f);
    *(float4*)&B1[cell] = z;
    *(float4*)&B0[cell] = z;
}

// 4 FDTD steps per launch. 256 blocks (4,4,16) = 1/CU, 1024 threads = 16 waves.
// Fixed ownership: thread t<441 owns a 4x4 pixel block of the 82^2 region for
// ALL substeps (pixels outside a substep's valid region are computed but
// provably never consumed; final store reads only the clean 64^2 interior).
__global__ __launch_bounds__(1024, 4) void fdtd4(
    const float* __restrict__ U1, const float* __restrict__ U0,   // padded
    const float* __restrict__ CD, const float* __restrict__ CG,   // padded
    const float* __restrict__ eff, const float* __restrict__ src,
    float* __restrict__ NU1, int n1bs, int n1rs, int n1off,
    float* __restrict__ NU0,                                      // padded
    int sbase)
{
    __shared__ __align__(16) float F[2][LR][LC];

    const int t  = threadIdx.x;
    const int bx = blockIdx.x, by = blockIdx.y, b = blockIdx.z;
    const int x0g = bx * 64 - 12, y0g = by * 64 - 12;
    const size_t pb = (size_t)b * PBS;

    // ---- stage F0 <- u_s, F1 <- u_{s-1}: 88 rows x 22 float4, no guards ----
    {
        const float* s1 = U1 + pb;
        const float* s0 = U0 + pb;
        #pragma unroll
        for (int rep = 0; rep < 2; ++rep) {
            const int i = t + rep * 1024;
            if (i < 88 * 22) {
                const int row = i / 22, q = (i - row * 22) * 4;
                const size_t g = (size_t)(by * 64 + row) * PC + (bx * 64 + q);
                *(float4*)&F[0][row][q] = *(const float4*)&s1[g];
                *(float4*)&F[1][row][q] = *(const float4*)&s0[g];
            }
        }
    }

    // ---- fixed ownership + coefficient registers (no guards: padded arrays) ----
    const int band = t / 21, cg = t - band * 21;        // t<441: 21x21 4x4-blocks
    const int ly0 = 3 + 4 * band, lx0 = 3 + 4 * cg;
    const int nR = (band == 20) ? 2 : 4;
    const int nC = (cg  == 20) ? 2 : 4;
    float cdv[4][4], cgv[4][4];
    if (t < 441) {
        #pragma unroll
        for (int k = 0; k < 4; ++k) {
            const size_t ci = pb + (size_t)(y0g + ly0 + k + 12) * PC
                                 + (x0g + lx0 + 13);
            const float4 d = *(const float4*)&CD[ci];
            const float4 g = *(const float4*)&CG[ci];
            cdv[k][0] = d.x; cdv[k][1] = d.y; cdv[k][2] = d.z; cdv[k][3] = d.w;
            cgv[k][0] = g.x; cgv[k][1] = g.y; cgv[k][2] = g.z; cgv[k][3] = g.w;
        }
    }
    __syncthreads();

    // ---- 4 substeps; code emitted ONCE (runtime sb loop keeps I$ small) ----
    #pragma unroll 1
    for (int sb = 0; sb < 4; ++sb) {
        if (t < 441) {
            const float (*Fs)[LC] = F[sb & 1];          // u_{s+sb}
            float (*Fd)[LC]       = F[(sb & 1) ^ 1];    // u_{s+sb-1} -> u_{s+sb+1}
            const float ds = src[2 * (sbase + sb)] - src[2 * (sbase + sb) + 1];
            const int cb = 4 * cg;                      // LDS col base (=lx0-3)

            float a[4][4] = {};
            float c[4][4];
            #pragma unroll
            for (int ky = 0; ky < 10; ++ky) {           // 10 rows feed 4 outputs
                const int yy = 4 * band + ky;
                const float4 q0 = *(const float4*)&Fs[yy][cb];
                const float4 q1 = *(const float4*)&Fs[yy][cb + 4];
                const float4 q2 = *(const float4*)&Fs[yy][cb + 8];
                const float v[12] = {q0.x, q0.y, q0.z, q0.w,
                                     q1.x, q1.y, q1.z, q1.w,
                                     q2.x, q2.y, q2.z, q2.w};
                if (ky >= 3 && ky <= 6) {               // center u1 capture
                    c[ky - 3][0] = v[3]; c[ky - 3][1] = v[4];
                    c[ky - 3][2] = v[5]; c[ky - 3][3] = v[6];
                }
                #pragma unroll
                for (int o = 0; o < 4; ++o) {
                    const int kh = ky - o;
                    if (kh >= 0 && kh < 7) {
                        #pragma unroll
                        for (int kx = 0; kx < 7; ++kx) {
                            const float E = eff[kh * 7 + kx];   // uniform s_load
                            a[o][0] = fmaf(v[kx],     E, a[o][0]);
                            a[o][1] = fmaf(v[kx + 1], E, a[o][1]);
                            a[o][2] = fmaf(v[kx + 2], E, a[o][2]);
                            a[o][3] = fmaf(v[kx + 3], E, a[o][3]);
                        }
                    }
                }
            }
            // epilogue: val = D1*conv + u1 + G*(u1-u0)  (+ source at (128,128))
            #pragma unroll
            for (int k = 0; k < 4; ++k) {
                if (k < nR) {
                    const int ly = ly0 + k;
                    const int gy = y0g + ly;
                    #pragma unroll
                    for (int cc = 0; cc < 4; ++cc) {
                        if (cc < nC) {
                            const float u1c = c[k][cc];
                            const float u0c = Fd[ly][lx0 + cc];
                            float val = fmaf(cdv[k][cc], a[k][cc],
                                         fmaf(cgv[k][cc], u1c - u0c, u1c));
                            if (gy == 128 && (x0g + lx0 + cc) == 128)
                                val = fmaf(-cdv[k][cc], ds, val);
                            Fd[ly][lx0 + cc] = val;
                        }
                    }
                }
            }
        }
        __syncthreads();
    }

    // ---- store clean interior: F0 = u_{s+4} -> NU1, F1 = u_{s+3} -> NU0 ----
    {
        const int row = t >> 4, q = (t & 15) * 4;       // 64 rows x 16 float4
        const int gy = by * 64 + row, gx = bx * 64 + q;
        const float4 o1 = *(const float4*)&F[0][12 + row][12 + q];
        const float4 o0 = *(const float4*)&F[1][12 + row][12 + q];
        *(float4*)&NU1[(size_t)b * n1bs + (size_t)(gy + n1off) * n1rs + gx + n1off] = o1;
        *(float4*)&NU0[(size_t)b * PBS + (size_t)(gy + 12) * PC + gx + 12] = o0;
    }
}

extern "C" void kernel_launch(void* const* d_in, const int* in_sizes, int n_in,
                              void* d_out, int out_size, void* d_ws, size_t ws_size,
                              hipStream_t stream) {
    (void)in_sizes; (void)n_in; (void)out_size; (void)ws_size;

    const float* u1    = (const float*)d_in[0];
    const float* u0    = (const float*)d_in[1];
    const float* epsr  = (const float*)d_in[2];
    const float* sigma = (const float*)d_in[3];
    const float* fdk   = (const float*)d_in[4];
    const float* cw    = (const float*)d_in[5];
    const float* src   = (const float*)d_in[6];

    float* eff = (float*)d_ws;          // 64 floats (256 B, keeps A1 16B-aligned)
    float* A1  = eff + 64;
    float* A0  = A1 + NPAD;
    float* B1  = A0 + NPAD;
    float* B0  = B1 + NPAD;
    float* CDg = B0 + NPAD;
    float* CGg = CDg + NPAD;            // total ~30.6 MB of ws

    prep_eff<<<1, 64, 0, stream>>>(fdk, cw, eff);
    prologue<<<(BATCH * PR * (PC / 4) + 255) / 256, 256, 0, stream>>>(
        u1, u0, epsr, sigma, A1, A0, B1, B0, CDg, CGg);

    dim3 grid(4, 4, BATCH);             // 256 blocks = 1/CU
    const float* cu1 = A1;
    const float* cu0 = A0;
    for (int j = 0; j < 8; ++j) {       // 8 x 4 fused steps = 32
        float* n1; float* n0;
        int bs = PBS, rs = PC, off = 12;
        if (j & 1) { n1 = A1; n0 = A0; } else { n1 = B1; n0 = B0; }
        if (j == 7) { n1 = (float*)d_out; bs = NPX; rs = DIM; off = 0; }
        fdtd4<<<grid, 1024, 0, stream>>>(cu1, cu0, CDg, CGg, eff, src,
                                         n1, bs, rs, off, n0, 4 * j);
        cu1 = (j & 1) ? A1 : B1;
        cu0 = (j & 1) ? A0 : B0;
    }
}